// Round 9
// baseline (158.538 us; speedup 1.0000x reference)
//
#include <hip/hip_runtime.h>

#define LOGZERO (-1.0e10f)

constexpr int BS    = 16;
constexpr int XMAX  = 512;
constexpr int VOCAB = 4000;
constexpr int YMAX  = 64;
constexpr int PF    = 8;    // DP ring depth for LDS loads AND alpha stores
constexpr int TCH   = 8;    // time-steps per gather block

// output layout (flat float32, reference return order)
constexpr size_t AS_OFF = 0;                                       // aligned_seq [16][512]
constexpr size_t TM_OFF = (size_t)BS * XMAX;                       // trigger_mask [16][65][512]
constexpr size_t YL_OFF = TM_OFF + (size_t)BS * (YMAX + 1) * XMAX; // ylens+1 [16]
constexpr size_t SC_OFF = YL_OFF + BS;                             // score [16]
// lpp[t][j] (j=0..63 odd labels, j=64 blank) lives in the TM region until the
// epilogue overwrites it with the real trigger_mask.
// d_ws: per-block alpha table, rows 0..512 of 128 floats: row t = alpha BEFORE step t
// (row 0 = init), interleaved per lane {aE,aO}. 16 * 513 * 512B = 4.2 MB.

constexpr int    ROWF       = 128;                   // floats per table row
constexpr size_t TBL_STRIDE = (size_t)(XMAX + 1) * ROWF;

__device__ __forceinline__ float dpp_shr1_f(float x, float fill) {
    // full-wave shift-down-by-1: lane i gets lane i-1's x; lane 0 gets `fill`
    return __int_as_float(__builtin_amdgcn_update_dpp(
        __float_as_int(fill), __float_as_int(x), 0x138 /*wave_shr:1*/, 0xF, 0xF, false));
}
__device__ __forceinline__ int dpp_shr1_i(int x, int fill) {
    return __builtin_amdgcn_update_dpp(fill, x, 0x138, 0xF, 0xF, false);
}
// identity DPP mov: bit-exact copy that regalloc cannot coalesce with the live source
__device__ __forceinline__ float dpp_id_f(float x) {
    return __int_as_float(__builtin_amdgcn_update_dpp(
        0, __float_as_int(x), 0xE4 /*quad_perm identity*/, 0xF, 0xF, false));
}

// ---------------- kernel 1: parallel gather of per-path log-probs ----------------
__global__ __launch_bounds__(64)
void gather_kernel(const float* __restrict__ ctc,
                   const int* __restrict__ ys,
                   const int* __restrict__ blank_p,
                   float* __restrict__ out)
{
    const int tc   = blockIdx.x;
    const int b    = blockIdx.y;
    const int lane = threadIdx.x;

    const int blank = blank_p[0];
    const int ysv   = ys[b * YMAX + lane];

    const float* base = ctc + ((size_t)b * XMAX + (size_t)tc * TCH) * VOCAB;

    float v[TCH];
    #pragma unroll
    for (int j = 0; j < TCH; ++j)
        v[j] = base[(size_t)j * VOCAB + ysv];
    const float bl = base[(size_t)(lane & (TCH - 1)) * VOCAB + blank];

    float* lpp = out + TM_OFF + (size_t)b * (YMAX + 1) * XMAX + (size_t)tc * TCH * 65;
    #pragma unroll
    for (int j = 0; j < TCH; ++j)
        lpp[(size_t)j * 65 + lane] = v[j];
    if (lane < TCH)
        lpp[(size_t)lane * 65 + 64] = bl;
}

// one DP time-step; K is a compile-time ring index.
// Stores the NEW alpha row (= row t+1) via a DPP-copied ring slot so the
// store-source clobber trails the store by PF iterations (vmcnt(PF-1), hidden).
#define DP_BODY(K)                                                             \
{                                                                              \
    const float lpO = rO[K], lpB = rB[K];                                      \
    rO[K] = lppL[offO]; rB[K] = lppL[offB]; offO += 65; offB += 65;            \
    const float prevO = dpp_shr1_f(aO, LOGZERO);                               \
    const float m2v   = sameO ? LOGZERO : prevO;                               \
    aO = fmaxf(fmaxf(aO, aE), m2v) + lpO;                                      \
    aE = fmaxf(aE, prevO) + lpB;                                               \
    ring[K].x = dpp_id_f(aE);                                                  \
    ring[K].y = dpp_id_f(aO);                                                  \
    *tp = ring[K];                                                             \
    tp += 64;                                                                  \
    ++t;                                                                       \
}

// ---------------- kernel 2: DP loop only (alpha rows -> d_ws) ----------------
__global__ __launch_bounds__(256)
void dp_loop_kernel(const int* __restrict__ src_size,
                    const int* __restrict__ ys,
                    const float* __restrict__ out,   // read-only here (lpp region)
                    float* __restrict__ ws)
{
    const int b    = blockIdx.x;
    const int tid  = threadIdx.x;          // wave 0 runs the DP
    const int lane = tid & 63;

    const int ss = src_size[b];

    __shared__ __align__(16) float lppL[(XMAX + PF) * 65];  // 135 KB, sole LDS user

    const float* gbase = out + TM_OFF + (size_t)b * (YMAX + 1) * XMAX;

    // ---- stage packed lpp into LDS (all 4 waves) ----
    {
        const float4* src = (const float4*)gbase;
        float4* dst = (float4*)lppL;
        #pragma unroll 4
        for (int i = tid; i < XMAX * 65 / 4; i += 256)
            dst[i] = src[i];
    }
    __syncthreads();

    // ---- wave 0: sequential DP; alpha rows -> d_ws table ----
    if (tid < 64) {
        const int  ysv    = ys[b * YMAX + lane];
        const int  ysPrev = dpp_shr1_i(ysv, -1);
        const bool sameO  = (ysv == ysPrev);

        float2* tp = (float2*)(ws + (size_t)b * TBL_STRIDE) + lane;

        // init row (row 0 = alpha before step 0)
        float2 iv; iv.x = (lane == 0) ? 0.0f : LOGZERO; iv.y = LOGZERO;
        *tp = iv; tp += 64;

        float rO[PF], rB[PF];
        #pragma unroll
        for (int k = 0; k < PF; ++k) {
            rO[k] = lppL[k * 65 + lane];
            rB[k] = lppL[k * 65 + 64];
        }

        float2 ring[PF];
        float aE = iv.x;        // alpha[2i]
        float aO = LOGZERO;     // alpha[2i+1]
        int offO = PF * 65 + lane, offB = PF * 65 + 64;
        int t = 0;

        while (t + PF <= ss) {
            #pragma unroll
            for (int k = 0; k < PF; ++k) DP_BODY(k)
        }
        #pragma unroll
        for (int k = 0; k < PF; ++k) { if (t < ss) DP_BODY(k) }
    }
}

// branch-free backtrace step at time T; A={bE,s1m}, S2=s2m plane, CC=c128 flag
#define BT(T, A, S2, CC) {                                                     \
    const int ct = ((T) == ssm1) ? ist : cur;                                  \
    states[(T)] = ((T) <= ssm1) ? ct : 0;                                      \
    const int h   = ct >> 1;                                                   \
    const int bEb = (int)((A.x >> h) & 1ULL);                                  \
    const int b1  = (int)((A.y >> h) & 1ULL);                                  \
    const int b2  = (int)((S2  >> h) & 1ULL);                                  \
    int code = (ct & 1) ? (b2 ? 2 : b1) : bEb;                                 \
    code = (ct == 128) ? (CC) : code;                                          \
    code = ((T) >= 1 && (T) <= ssm1) ? code : 0;                               \
    cur = ct - code;                                                           \
}

// ---------------- kernel 3: decisions + backtrace + epilogue ----------------
__global__ __launch_bounds__(256)
void bt_epi_kernel(const int* __restrict__ src_size,
                   const int* __restrict__ ys,
                   const int* __restrict__ ylens,
                   const int* __restrict__ blank_p,
                   float* __restrict__ out,
                   const float* __restrict__ ws)
{
    const int b    = blockIdx.x;
    const int tid  = threadIdx.x;
    const int lane = tid & 63;
    const int w    = tid >> 6;

    const int blank = blank_p[0];
    const int ss    = src_size[b];
    const int ylen  = ylens[b];
    const int plen  = 2 * ylen + 1;

    __shared__ ulonglong2 PLA[XMAX];        // {bE plane, s1 plane}
    __shared__ unsigned long long S2M[XMAX];// s2 plane
    __shared__ int   C1[XMAX];              // state-128 decision per t
    __shared__ float aO63[XMAX];            // A[t].aO[63]
    __shared__ float lpBs[XMAX];            // blank lp per t
    __shared__ int   states[XMAX];
    __shared__ int   trig[XMAX];
    __shared__ int   ysL[YMAX];
    __shared__ float aXfin;
    __shared__ int   istS;

    const float* tbl  = ws + (size_t)b * TBL_STRIDE;
    float*       gbase = out + TM_OFF + (size_t)b * (YMAX + 1) * XMAX;

    // ---- phase A: stage scan inputs + labels ----
    for (int t = tid; t < XMAX; t += 256) {
        aO63[t] = tbl[(size_t)t * ROWF + 127];
        lpBs[t] = gbase[(size_t)t * 65 + 64];
    }
    if (tid < YMAX) ysL[tid] = ys[b * YMAX + tid];
    __syncthreads();

    // ---- phase B (thread 0): serial aX chain -> c128 bits; phase C (waves 1-3):
    //      parallel decision recompute from alpha rows -> bit planes ----
    if (w == 0) {
        if (lane == 0) {
            float aX = LOGZERO;
            #pragma unroll 4
            for (int t = 0; t < XMAX; ++t) {
                const float ao = aO63[t];
                int c = 0;
                if (t < ss) {
                    c = (ao > aX) ? 1 : 0;
                    aX = fmaxf(aX, ao) + lpBs[t];
                }
                C1[t] = c;
            }
            aXfin = aX;     // alpha[128] after ss steps
        }
    } else {
        const int  ysv    = ysL[lane];
        const int  ysPrev = dpp_shr1_i(ysv, -1);
        const bool sameO  = (ysv == ysPrev);
        for (int t = w - 1; t < XMAX; t += 3) {
            const float2 v  = *(const float2*)(tbl + (size_t)t * ROWF + lane * 2);
            const float prevO = dpp_shr1_f(v.y, LOGZERO);
            const float m2v   = sameO ? LOGZERO : prevO;
            const unsigned long long mE = __ballot(prevO > v.x);
            const unsigned long long m1 = __ballot(v.x > v.y);
            const unsigned long long m2 = __ballot(m2v > fmaxf(v.y, v.x));
            if (lane == 0) {
                ulonglong2 pv; pv.x = mE; pv.y = m1;
                PLA[t] = pv;
                S2M[t] = m2;
            }
        }
    }
    __syncthreads();

    // ---- phase D (wave 0): scores + initial backtrace state ----
    if (tid < 64) {
        const float2 vf = *(const float2*)(tbl + (size_t)ss * ROWF + lane * 2);
        const float s1e = __shfl(vf.x, ylen);
        const float s1v = (ylen == YMAX) ? aXfin : s1e;
        const float s2v = __shfl(vf.y, ylen - 1);
        if (lane == 0) {
            out[SC_OFF + b] = fmaxf(s1v, s2v);
            out[YL_OFF + b] = (float)(ylen + 1);
            istS = (s1v > s2v) ? (plen - 1) : (plen - 2);
        }
    }
    __syncthreads();

    // ---- phase E (thread 0): branch-free backtrace, 4-deep pipelined ----
    if (tid == 0) {
        const int ist  = istS;
        const int ssm1 = ss - 1;
        int cur = 0;
        ulonglong2 a0 = PLA[XMAX-1], a1 = PLA[XMAX-2], a2 = PLA[XMAX-3], a3 = PLA[XMAX-4];
        unsigned long long s0 = S2M[XMAX-1], s1 = S2M[XMAX-2], s2 = S2M[XMAX-3], s3 = S2M[XMAX-4];
        int c0 = C1[XMAX-1], c1 = C1[XMAX-2], c2 = C1[XMAX-3], c3 = C1[XMAX-4];
        for (int tg = XMAX - 1; tg >= 3; tg -= 4) {
            ulonglong2 na0, na1, na2, na3;
            unsigned long long ns0, ns1, ns2, ns3;
            int nc0, nc1, nc2, nc3;
            const bool more = (tg >= 7);
            if (more) {
                na0 = PLA[tg-4]; ns0 = S2M[tg-4]; nc0 = C1[tg-4];
                na1 = PLA[tg-5]; ns1 = S2M[tg-5]; nc1 = C1[tg-5];
                na2 = PLA[tg-6]; ns2 = S2M[tg-6]; nc2 = C1[tg-6];
                na3 = PLA[tg-7]; ns3 = S2M[tg-7]; nc3 = C1[tg-7];
            }
            BT(tg,     a0, s0, c0);
            BT(tg - 1, a1, s1, c1);
            BT(tg - 2, a2, s2, c2);
            BT(tg - 3, a3, s3, c3);
            if (more) {
                a0 = na0; s0 = ns0; c0 = nc0;
                a1 = na1; s1 = ns1; c1 = nc1;
                a2 = na2; s2 = ns2; c2 = nc2;
                a3 = na3; s3 = ns3; c3 = nc3;
            }
        }
    }
    __syncthreads();

    // ---- phase F (wave 0): states -> labels, collapse, aligned_seq, trig scan ----
    if (tid < 64) {
        const int t8 = lane * 8;
        int sq[8];
        #pragma unroll
        for (int j = 0; j < 8; ++j) {
            const int st = states[t8 + j];
            sq[j] = (st & 1) ? ysL[st >> 1] : blank;
        }
        int prevLast = __shfl_up(sq[7], 1);
        if (lane == 0) prevLast = 0;

        int cl[8];
        #pragma unroll
        for (int j = 0; j < 8; ++j) {
            const int pv = j ? sq[j - 1] : prevLast;
            cl[j] = (sq[j] == pv) ? 0 : sq[j];
        }

        {   // aligned_seq out
            float* as = out + AS_OFF + (size_t)b * XMAX + t8;
            float4 o0, o1;
            o0.x = (float)cl[0]; o0.y = (float)cl[1]; o0.z = (float)cl[2]; o0.w = (float)cl[3];
            o1.x = (float)cl[4]; o1.y = (float)cl[5]; o1.z = (float)cl[6]; o1.w = (float)cl[7];
            *(float4*)as = o0; *((float4*)as + 1) = o1;
        }

        int cnt = 0;
        #pragma unroll
        for (int j = 0; j < 8; ++j) cnt += (cl[j] != blank);
        int x = cnt;
        #pragma unroll
        for (int d = 1; d < 64; d <<= 1) {
            const int y = __shfl_up(x, d);
            if (lane >= d) x += y;
        }
        int run = x - cnt + ((0 != blank) ? 1 : 0);
        #pragma unroll
        for (int j = 0; j < 8; ++j) {
            trig[t8 + j] = run;
            run += (cl[j] != blank);
        }
    }
    __syncthreads();

    // ---- phase G (all 256): trigger mask overwrites the lpp scratch region ----
    float* tm = gbase;
    for (int i4 = tid * 4; i4 < (YMAX + 1) * XMAX; i4 += 256 * 4) {
        const int y  = i4 >> 9;
        const int t0 = i4 & (XMAX - 1);
        const int4 tg4 = *(const int4*)&trig[t0];
        float4 v;
        if (y == YMAX) {
            v.x = ((tg4.x == YMAX && (t0 + 0) < ss) || (t0 + 0) == ss - 1) ? 1.0f : 0.0f;
            v.y = ((tg4.y == YMAX && (t0 + 1) < ss) || (t0 + 1) == ss - 1) ? 1.0f : 0.0f;
            v.z = ((tg4.z == YMAX && (t0 + 2) < ss) || (t0 + 2) == ss - 1) ? 1.0f : 0.0f;
            v.w = ((tg4.w == YMAX && (t0 + 3) < ss) || (t0 + 3) == ss - 1) ? 1.0f : 0.0f;
        } else {
            v.x = (tg4.x == y) ? 1.0f : 0.0f;
            v.y = (tg4.y == y) ? 1.0f : 0.0f;
            v.z = (tg4.z == y) ? 1.0f : 0.0f;
            v.w = (tg4.w == y) ? 1.0f : 0.0f;
        }
        *(float4*)(tm + i4) = v;
    }
}

extern "C" void kernel_launch(void* const* d_in, const int* in_sizes, int n_in,
                              void* d_out, int out_size, void* d_ws, size_t ws_size,
                              hipStream_t stream) {
    (void)in_sizes; (void)n_in; (void)ws_size; (void)out_size;
    const float* ctc      = (const float*)d_in[0];
    // d_in[1] = src_mask — derivable from src_size, unused
    const int*   src_size = (const int*)d_in[2];
    const int*   ys       = (const int*)d_in[3];
    const int*   ylens    = (const int*)d_in[4];
    const int*   blank    = (const int*)d_in[5];
    float*       out      = (float*)d_out;
    float*       ws       = (float*)d_ws;

    dim3 g1(XMAX / TCH, BS);
    gather_kernel<<<g1, 64, 0, stream>>>(ctc, ys, blank, out);
    dp_loop_kernel<<<BS, 256, 0, stream>>>(src_size, ys, out, ws);
    bt_epi_kernel<<<BS, 256, 0, stream>>>(src_size, ys, ylens, blank, out, ws);
}

// Round 10
// 120.961 us; speedup vs baseline: 1.3107x; 1.3107x over previous
//
#include <hip/hip_runtime.h>

#define LOGZERO (-1.0e10f)

constexpr int BS    = 16;
constexpr int XMAX  = 512;
constexpr int VOCAB = 4000;
constexpr int YMAX  = 64;
constexpr int PF    = 8;    // DP ring depth for LDS loads AND alpha stores
constexpr int TCH   = 8;    // time-steps per gather block

// output layout (flat float32, reference return order)
constexpr size_t AS_OFF = 0;                                       // aligned_seq [16][512]
constexpr size_t TM_OFF = (size_t)BS * XMAX;                       // trigger_mask [16][65][512]
constexpr size_t YL_OFF = TM_OFF + (size_t)BS * (YMAX + 1) * XMAX; // ylens+1 [16]
constexpr size_t SC_OFF = YL_OFF + BS;                             // score [16]
// lpp[t][j] (j=0..63 odd labels, j=64 blank) lives in the TM region until the
// epilogue overwrites it with the real trigger_mask.
// d_ws: per-block alpha table, rows 0..512 of 128 floats: row t = alpha BEFORE step t
// (row 0 = init), interleaved per lane {aE,aO}. 16 * 513 * 512B = 4.2 MB.

constexpr int    ROWF       = 128;                   // floats per table row
constexpr size_t TBL_STRIDE = (size_t)(XMAX + 1) * ROWF;

__device__ __forceinline__ float dpp_shr1_f(float x, float fill) {
    // full-wave shift-down-by-1: lane i gets lane i-1's x; lane 0 gets `fill`
    return __int_as_float(__builtin_amdgcn_update_dpp(
        __float_as_int(fill), __float_as_int(x), 0x138 /*wave_shr:1*/, 0xF, 0xF, false));
}
__device__ __forceinline__ int dpp_shr1_i(int x, int fill) {
    return __builtin_amdgcn_update_dpp(fill, x, 0x138, 0xF, 0xF, false);
}
// identity DPP mov: bit-exact copy that regalloc cannot coalesce with the live source
__device__ __forceinline__ float dpp_id_f(float x) {
    return __int_as_float(__builtin_amdgcn_update_dpp(
        0, __float_as_int(x), 0xE4 /*quad_perm identity*/, 0xF, 0xF, false));
}

// ---------------- kernel 1: parallel gather of per-path log-probs ----------------
__global__ __launch_bounds__(64)
void gather_kernel(const float* __restrict__ ctc,
                   const int* __restrict__ ys,
                   const int* __restrict__ blank_p,
                   float* __restrict__ out)
{
    const int tc   = blockIdx.x;
    const int b    = blockIdx.y;
    const int lane = threadIdx.x;

    const int blank = blank_p[0];
    const int ysv   = ys[b * YMAX + lane];

    const float* base = ctc + ((size_t)b * XMAX + (size_t)tc * TCH) * VOCAB;

    float v[TCH];
    #pragma unroll
    for (int j = 0; j < TCH; ++j)
        v[j] = base[(size_t)j * VOCAB + ysv];
    const float bl = base[(size_t)(lane & (TCH - 1)) * VOCAB + blank];

    float* lpp = out + TM_OFF + (size_t)b * (YMAX + 1) * XMAX + (size_t)tc * TCH * 65;
    #pragma unroll
    for (int j = 0; j < TCH; ++j)
        lpp[(size_t)j * 65 + lane] = v[j];
    if (lane < TCH)
        lpp[(size_t)lane * 65 + 64] = bl;
}

// one DP time-step; K is a compile-time ring index.
// Stores the NEW alpha row (= row t+1) via a DPP-copied ring slot so the
// store-source clobber trails the store by PF iterations (vmcnt hidden).
#define DP_BODY(K)                                                             \
{                                                                              \
    const float lpO = rO[K], lpB = rB[K];                                      \
    rO[K] = lppL[offO]; rB[K] = lppL[offB]; offO += 65; offB += 65;            \
    const float prevO = dpp_shr1_f(aO, LOGZERO);                               \
    const float m2v   = sameO ? LOGZERO : prevO;                               \
    aO = fmaxf(fmaxf(aO, aE), m2v) + lpO;                                      \
    aE = fmaxf(aE, prevO) + lpB;                                               \
    ring[K].x = dpp_id_f(aE);                                                  \
    ring[K].y = dpp_id_f(aO);                                                  \
    *tp = ring[K];                                                             \
    tp += 64;                                                                  \
    ++t;                                                                       \
}

// ---------------- kernel 2: DP loop only (alpha rows -> d_ws) ----------------
__global__ __launch_bounds__(256)
void dp_loop_kernel(const int* __restrict__ src_size,
                    const int* __restrict__ ys,
                    const float* __restrict__ out,   // read-only here (lpp region)
                    float* __restrict__ ws)
{
    const int b    = blockIdx.x;
    const int tid  = threadIdx.x;          // wave 0 runs the DP
    const int lane = tid & 63;

    const int ss = src_size[b];

    __shared__ __align__(16) float lppL[(XMAX + PF) * 65];  // 135 KB, sole LDS user

    const float* gbase = out + TM_OFF + (size_t)b * (YMAX + 1) * XMAX;

    // ---- stage packed lpp into LDS (all 4 waves) ----
    {
        const float4* src = (const float4*)gbase;
        float4* dst = (float4*)lppL;
        #pragma unroll 4
        for (int i = tid; i < XMAX * 65 / 4; i += 256)
            dst[i] = src[i];
    }
    __syncthreads();

    // ---- wave 0: sequential DP; alpha rows -> d_ws table ----
    if (tid < 64) {
        const int  ysv    = ys[b * YMAX + lane];
        const int  ysPrev = dpp_shr1_i(ysv, -1);
        const bool sameO  = (ysv == ysPrev);

        float2* tp = (float2*)(ws + (size_t)b * TBL_STRIDE) + lane;

        // init row (row 0 = alpha before step 0)
        float2 iv; iv.x = (lane == 0) ? 0.0f : LOGZERO; iv.y = LOGZERO;
        *tp = iv; tp += 64;

        float rO[PF], rB[PF];
        #pragma unroll
        for (int k = 0; k < PF; ++k) {
            rO[k] = lppL[k * 65 + lane];
            rB[k] = lppL[k * 65 + 64];
        }

        float2 ring[PF];
        float aE = iv.x;        // alpha[2i]
        float aO = LOGZERO;     // alpha[2i+1]
        int offO = PF * 65 + lane, offB = PF * 65 + 64;
        int t = 0;

        while (t + PF <= ss) {
            #pragma unroll
            for (int k = 0; k < PF; ++k) DP_BODY(k)
        }
        #pragma unroll
        for (int k = 0; k < PF; ++k) { if (t < ss) DP_BODY(k) }
    }
}

// branch-free backtrace step at time T; A={bE,s1m}, S2=s2m plane, CC=c128 flag
#define BT(T, A, S2, CC) {                                                     \
    const int ct = ((T) == ssm1) ? ist : cur;                                  \
    states[(T)] = ((T) <= ssm1) ? ct : 0;                                      \
    const int h   = ct >> 1;                                                   \
    const int bEb = (int)((A.x >> h) & 1ULL);                                  \
    const int b1  = (int)((A.y >> h) & 1ULL);                                  \
    const int b2  = (int)((S2  >> h) & 1ULL);                                  \
    int code = (ct & 1) ? (b2 ? 2 : b1) : bEb;                                 \
    code = (ct == 128) ? (CC) : code;                                          \
    code = ((T) >= 1 && (T) <= ssm1) ? code : 0;                               \
    cur = ct - code;                                                           \
}

// ---------------- kernel 3: decisions + backtrace + epilogue ----------------
__global__ __launch_bounds__(256)
void bt_epi_kernel(const int* __restrict__ src_size,
                   const int* __restrict__ ys,
                   const int* __restrict__ ylens,
                   const int* __restrict__ blank_p,
                   float* __restrict__ out,
                   const float* __restrict__ ws)
{
    const int b    = blockIdx.x;
    const int tid  = threadIdx.x;
    const int lane = tid & 63;
    const int w    = tid >> 6;

    const int blank = blank_p[0];
    const int ss    = src_size[b];
    const int ylen  = ylens[b];
    const int plen  = 2 * ylen + 1;

    __shared__ ulonglong2 PLA[XMAX];        // {bE plane, s1 plane}
    __shared__ unsigned long long S2M[XMAX];// s2 plane
    __shared__ int   C1[XMAX];              // state-128 decision per t
    __shared__ float aO63[XMAX];            // A[t].aO[63]
    __shared__ float lpBs[XMAX];            // blank lp per t
    __shared__ int   states[XMAX];
    __shared__ int   trig[XMAX];
    __shared__ int   ysL[YMAX];
    __shared__ float aXfin;
    __shared__ int   istS;

    const float* tbl   = ws + (size_t)b * TBL_STRIDE;
    float*       gbase = out + TM_OFF + (size_t)b * (YMAX + 1) * XMAX;

    // ---- phase A: stage scan inputs + labels ----
    for (int t = tid; t < XMAX; t += 256) {
        aO63[t] = tbl[(size_t)t * ROWF + 127];
        lpBs[t] = gbase[(size_t)t * 65 + 64];
    }
    if (tid < YMAX) ysL[tid] = ys[b * YMAX + tid];
    __syncthreads();

    // ---- phase B' (thread 0, branchless+unrolled): serial aX chain -> C1 bits
    //      runs CONCURRENTLY with phase C' on waves 1-3 ----
    if (w == 0) {
        if (lane == 0) {
            float aX = LOGZERO;
            #pragma unroll 8
            for (int t = 0; t < XMAX; ++t) {
                const float ao = aO63[t];
                const float lb = lpBs[t];
                const bool cond = (t < ss);
                C1[t] = (cond && (ao > aX)) ? 1 : 0;
                const float nx = fmaxf(aX, ao) + lb;
                aX = cond ? nx : aX;
            }
            aXfin = aX;     // alpha[128] after ss steps
        }
    } else {
        // ---- phase C' (waves 1-3): decision recompute, 8-deep batched loads ----
        const int  ysv    = ysL[lane];
        const int  ysPrev = dpp_shr1_i(ysv, -1);
        const bool sameO  = (ysv == ysPrev);
        for (int g = w - 1; g < XMAX / 8; g += 3) {     // 8-row blocks, 3-interleaved
            float2 v[8];
            #pragma unroll
            for (int j = 0; j < 8; ++j)
                v[j] = *(const float2*)(tbl + (size_t)(g * 8 + j) * ROWF + lane * 2);
            #pragma unroll
            for (int j = 0; j < 8; ++j) {
                const int t = g * 8 + j;
                const float prevO = dpp_shr1_f(v[j].y, LOGZERO);
                const float m2v   = sameO ? LOGZERO : prevO;
                const unsigned long long mE = __ballot(prevO > v[j].x);
                const unsigned long long m1 = __ballot(v[j].x > v[j].y);
                const unsigned long long m2 = __ballot(m2v > fmaxf(v[j].y, v[j].x));
                if (lane == 0) {
                    ulonglong2 pv; pv.x = mE; pv.y = m1;
                    PLA[t] = pv;
                    S2M[t] = m2;
                }
            }
        }
    }
    __syncthreads();

    // ---- phase D (wave 0): scores + initial backtrace state ----
    if (tid < 64) {
        const float2 vf = *(const float2*)(tbl + (size_t)ss * ROWF + lane * 2);
        const float s1e = __shfl(vf.x, ylen);
        const float s1v = (ylen == YMAX) ? aXfin : s1e;
        const float s2v = __shfl(vf.y, ylen - 1);
        if (lane == 0) {
            out[SC_OFF + b] = fmaxf(s1v, s2v);
            out[YL_OFF + b] = (float)(ylen + 1);
            istS = (s1v > s2v) ? (plen - 1) : (plen - 2);
        }
    }
    __syncthreads();

    // ---- phase E (thread 0): branch-free backtrace, 4-deep pipelined ----
    if (tid == 0) {
        const int ist  = istS;
        const int ssm1 = ss - 1;
        int cur = 0;
        ulonglong2 a0 = PLA[XMAX-1], a1 = PLA[XMAX-2], a2 = PLA[XMAX-3], a3 = PLA[XMAX-4];
        unsigned long long s0 = S2M[XMAX-1], s1 = S2M[XMAX-2], s2 = S2M[XMAX-3], s3 = S2M[XMAX-4];
        int c0 = C1[XMAX-1], c1 = C1[XMAX-2], c2 = C1[XMAX-3], c3 = C1[XMAX-4];
        for (int tg = XMAX - 1; tg >= 3; tg -= 4) {
            ulonglong2 na0, na1, na2, na3;
            unsigned long long ns0, ns1, ns2, ns3;
            int nc0, nc1, nc2, nc3;
            const bool more = (tg >= 7);
            if (more) {
                na0 = PLA[tg-4]; ns0 = S2M[tg-4]; nc0 = C1[tg-4];
                na1 = PLA[tg-5]; ns1 = S2M[tg-5]; nc1 = C1[tg-5];
                na2 = PLA[tg-6]; ns2 = S2M[tg-6]; nc2 = C1[tg-6];
                na3 = PLA[tg-7]; ns3 = S2M[tg-7]; nc3 = C1[tg-7];
            }
            BT(tg,     a0, s0, c0);
            BT(tg - 1, a1, s1, c1);
            BT(tg - 2, a2, s2, c2);
            BT(tg - 3, a3, s3, c3);
            if (more) {
                a0 = na0; s0 = ns0; c0 = nc0;
                a1 = na1; s1 = ns1; c1 = nc1;
                a2 = na2; s2 = ns2; c2 = nc2;
                a3 = na3; s3 = ns3; c3 = nc3;
            }
        }
    }
    __syncthreads();

    // ---- phase F (wave 0): states -> labels, collapse, aligned_seq, trig scan ----
    if (tid < 64) {
        const int t8 = lane * 8;
        int sq[8];
        #pragma unroll
        for (int j = 0; j < 8; ++j) {
            const int st = states[t8 + j];
            sq[j] = (st & 1) ? ysL[st >> 1] : blank;
        }
        int prevLast = __shfl_up(sq[7], 1);
        if (lane == 0) prevLast = 0;

        int cl[8];
        #pragma unroll
        for (int j = 0; j < 8; ++j) {
            const int pv = j ? sq[j - 1] : prevLast;
            cl[j] = (sq[j] == pv) ? 0 : sq[j];
        }

        {   // aligned_seq out
            float* as = out + AS_OFF + (size_t)b * XMAX + t8;
            float4 o0, o1;
            o0.x = (float)cl[0]; o0.y = (float)cl[1]; o0.z = (float)cl[2]; o0.w = (float)cl[3];
            o1.x = (float)cl[4]; o1.y = (float)cl[5]; o1.z = (float)cl[6]; o1.w = (float)cl[7];
            *(float4*)as = o0; *((float4*)as + 1) = o1;
        }

        int cnt = 0;
        #pragma unroll
        for (int j = 0; j < 8; ++j) cnt += (cl[j] != blank);
        int x = cnt;
        #pragma unroll
        for (int d = 1; d < 64; d <<= 1) {
            const int y = __shfl_up(x, d);
            if (lane >= d) x += y;
        }
        int run = x - cnt + ((0 != blank) ? 1 : 0);
        #pragma unroll
        for (int j = 0; j < 8; ++j) {
            trig[t8 + j] = run;
            run += (cl[j] != blank);
        }
    }
    __syncthreads();

    // ---- phase G (all 256): trigger mask overwrites the lpp scratch region ----
    float* tm = gbase;
    for (int i4 = tid * 4; i4 < (YMAX + 1) * XMAX; i4 += 256 * 4) {
        const int y  = i4 >> 9;
        const int t0 = i4 & (XMAX - 1);
        const int4 tg4 = *(const int4*)&trig[t0];
        float4 v;
        if (y == YMAX) {
            v.x = ((tg4.x == YMAX && (t0 + 0) < ss) || (t0 + 0) == ss - 1) ? 1.0f : 0.0f;
            v.y = ((tg4.y == YMAX && (t0 + 1) < ss) || (t0 + 1) == ss - 1) ? 1.0f : 0.0f;
            v.z = ((tg4.z == YMAX && (t0 + 2) < ss) || (t0 + 2) == ss - 1) ? 1.0f : 0.0f;
            v.w = ((tg4.w == YMAX && (t0 + 3) < ss) || (t0 + 3) == ss - 1) ? 1.0f : 0.0f;
        } else {
            v.x = (tg4.x == y) ? 1.0f : 0.0f;
            v.y = (tg4.y == y) ? 1.0f : 0.0f;
            v.z = (tg4.z == y) ? 1.0f : 0.0f;
            v.w = (tg4.w == y) ? 1.0f : 0.0f;
        }
        *(float4*)(tm + i4) = v;
    }
}

extern "C" void kernel_launch(void* const* d_in, const int* in_sizes, int n_in,
                              void* d_out, int out_size, void* d_ws, size_t ws_size,
                              hipStream_t stream) {
    (void)in_sizes; (void)n_in; (void)ws_size; (void)out_size;
    const float* ctc      = (const float*)d_in[0];
    // d_in[1] = src_mask — derivable from src_size, unused
    const int*   src_size = (const int*)d_in[2];
    const int*   ys       = (const int*)d_in[3];
    const int*   ylens    = (const int*)d_in[4];
    const int*   blank    = (const int*)d_in[5];
    float*       out      = (float*)d_out;
    float*       ws       = (float*)d_ws;

    dim3 g1(XMAX / TCH, BS);
    gather_kernel<<<g1, 64, 0, stream>>>(ctc, ys, blank, out);
    dp_loop_kernel<<<BS, 256, 0, stream>>>(src_size, ys, out, ws);
    bt_epi_kernel<<<BS, 256, 0, stream>>>(src_size, ys, ylens, blank, out, ws);
}